// Round 4
// baseline (100.458 us; speedup 1.0000x reference)
//
#include <hip/hip_runtime.h>

// PCEN with 10 smoothing rates. x:(B,F,T) f32 -> out:(B,R,F,T) f32
//
// R3 -> R4 restructure: one wave owns one (b,f) row and FIVE rates (rg picks
// rates rg*5..rg*5+4). x is loaded once per wave (was 10 reads per row),
// and each wave carries 5 independent recurrence chains -> 5x ILP on the
// serial shuffle-scan, hiding ds_bpermute latency at 4 waves/SIMD.
// Per-rate constants are wave-uniform -> forced to SGPRs via readfirstlane.
//
// Recurrence y_t = a*y_{t-1} + s*x_t, y_0 = x_0 (seed carry=x_0, a+s=1).
// Per 512-elem chunk: lane loads 8 floats (2x float4), 8-elem local scan,
// 6-step shuffle scan (multipliers a^8..a^256), fixup, PCEN epilogue via
// native exp2/log2, nontemporal float4 stores.

typedef float f32x4 __attribute__((ext_vector_type(4)));

constexpr int B_ = 16, F_ = 128, T_ = 4000, R_ = 10;
constexpr float EPS_ = 1e-5f;
constexpr int RPW = 5, NRG = R_ / RPW;   // 5 rates/wave, 2 rate-groups
constexpr int TPB = 256, WPB = TPB / 64;

__device__ __forceinline__ float rfl(float v) {
    return __int_as_float(__builtin_amdgcn_readfirstlane(__float_as_int(v)));
}

__global__ __launch_bounds__(TPB) void pcen_kernel(
    const float* __restrict__ x,
    const float* __restrict__ s_log,
    const float* __restrict__ alpha_log,
    const float* __restrict__ delta_log,
    const float* __restrict__ r_log,
    float* __restrict__ out)
{
    const int wid  = blockIdx.x * WPB + (threadIdx.x >> 6);
    const int lane = threadIdx.x & 63;

    // wid = (b*NRG + rg)*F + f : block's 4 waves = consecutive f -> each of the
    // 5 written rate-planes gets 4 consecutive 16KB rows (64KB dense/block).
    const int b   = wid / (NRG * F_);
    const int rem = wid - b * (NRG * F_);
    const int rg  = rem / F_;
    const int f   = rem - rg * F_;

    const float alpha   = rfl(__builtin_expf(alpha_log[f]));
    const float delta   = rfl(__builtin_expf(delta_log[f]));
    const float r       = rfl(__builtin_expf(r_log[f]));
    const float delta_r = rfl(__builtin_exp2f(r * __builtin_log2f(delta)));

    // per-rate wave-uniform constants -> SGPRs
    float sv[RPW], a1[RPW], p2[RPW], p3[RPW], p4[RPW], p5[RPW], p6[RPW], p7[RPW],
          p8[RPW], p16[RPW], p32[RPW], p64[RPW], p128[RPW], p256[RPW];
    float carry[RPW];
    const float* xrow = x + (size_t)(b * F_ + f) * T_;
    float* orow[RPW];

#pragma unroll
    for (int rr = 0; rr < RPW; ++rr) {
        const int rate = rg * RPW + rr;
        const float s_ = rfl(__builtin_expf(s_log[rate * F_ + f]));
        const float a_ = 1.0f - s_;
        sv[rr] = s_;  a1[rr] = a_;
        p2[rr]  = rfl(a_ * a_);
        p3[rr]  = rfl(p2[rr] * a_);
        p4[rr]  = rfl(p2[rr] * p2[rr]);
        p5[rr]  = rfl(p4[rr] * a_);
        p6[rr]  = rfl(p4[rr] * p2[rr]);
        p7[rr]  = rfl(p4[rr] * p3[rr]);
        p8[rr]  = rfl(p4[rr] * p4[rr]);
        p16[rr] = rfl(p8[rr] * p8[rr]);
        p32[rr] = rfl(p16[rr] * p16[rr]);
        p64[rr] = rfl(p32[rr] * p32[rr]);
        p128[rr] = rfl(p64[rr] * p64[rr]);
        p256[rr] = rfl(p128[rr] * p128[rr]);
        carry[rr] = xrow[0];                       // y_{-1} := x_0
        orow[rr]  = out + (size_t)((b * R_ + rate) * F_ + f) * T_;
    }

    auto pcen1 = [&](float xv, float m) -> float {
        const float sm = __builtin_exp2f(-alpha * __builtin_log2f(EPS_ + m));
        return __builtin_exp2f(r * __builtin_log2f(fmaf(xv, sm, delta))) - delta_r;
    };

    for (int t0 = 0; t0 < T_; t0 += 512) {
        const int t = t0 + lane * 8;
        const bool act = (t < T_);                 // T_%8==0: active lanes full
        float4 v0 = make_float4(0.f, 0.f, 0.f, 0.f);
        float4 v1 = make_float4(0.f, 0.f, 0.f, 0.f);
        if (act) {
            v0 = *reinterpret_cast<const float4*>(xrow + t);
            v1 = *reinterpret_cast<const float4*>(xrow + t + 4);
        }

#pragma unroll
        for (int rr = 0; rr < RPW; ++rr) {
            const float s_ = sv[rr], a_ = a1[rr];

            const float l0 = s_ * v0.x;
            const float l1 = fmaf(a_, l0, s_ * v0.y);
            const float l2 = fmaf(a_, l1, s_ * v0.z);
            const float l3 = fmaf(a_, l2, s_ * v0.w);
            const float l4 = fmaf(a_, l3, s_ * v1.x);
            const float l5 = fmaf(a_, l4, s_ * v1.y);
            const float l6 = fmaf(a_, l5, s_ * v1.z);
            const float l7 = fmaf(a_, l6, s_ * v1.w);

            float Y = l7;
            if (lane == 0) Y = fmaf(p8[rr], carry[rr], Y);

            float up;
            up = __shfl_up(Y, 1);  if (lane >= 1)  Y = fmaf(p8[rr],   up, Y);
            up = __shfl_up(Y, 2);  if (lane >= 2)  Y = fmaf(p16[rr],  up, Y);
            up = __shfl_up(Y, 4);  if (lane >= 4)  Y = fmaf(p32[rr],  up, Y);
            up = __shfl_up(Y, 8);  if (lane >= 8)  Y = fmaf(p64[rr],  up, Y);
            up = __shfl_up(Y, 16); if (lane >= 16) Y = fmaf(p128[rr], up, Y);
            up = __shfl_up(Y, 32); if (lane >= 32) Y = fmaf(p256[rr], up, Y);

            float yin = __shfl_up(Y, 1);
            if (lane == 0) yin = carry[rr];
            carry[rr] = __shfl(Y, 63);             // chunk-exit state

            if (act) {
                const float m0 = fmaf(a_,     yin, l0);
                const float m1 = fmaf(p2[rr], yin, l1);
                const float m2 = fmaf(p3[rr], yin, l2);
                const float m3 = fmaf(p4[rr], yin, l3);
                const float m4 = fmaf(p5[rr], yin, l4);
                const float m5 = fmaf(p6[rr], yin, l5);
                const float m6 = fmaf(p7[rr], yin, l6);
                const float m7 = fmaf(p8[rr], yin, l7);

                f32x4 o0, o1;
                o0.x = pcen1(v0.x, m0);
                o0.y = pcen1(v0.y, m1);
                o0.z = pcen1(v0.z, m2);
                o0.w = pcen1(v0.w, m3);
                o1.x = pcen1(v1.x, m4);
                o1.y = pcen1(v1.y, m5);
                o1.z = pcen1(v1.z, m6);
                o1.w = pcen1(v1.w, m7);
                __builtin_nontemporal_store(o0, reinterpret_cast<f32x4*>(orow[rr] + t));
                __builtin_nontemporal_store(o1, reinterpret_cast<f32x4*>(orow[rr] + t + 4));
            }
        }
    }
}

extern "C" void kernel_launch(void* const* d_in, const int* in_sizes, int n_in,
                              void* d_out, int out_size, void* d_ws, size_t ws_size,
                              hipStream_t stream) {
    const float* x         = (const float*)d_in[0];
    const float* s_log     = (const float*)d_in[1];
    const float* alpha_log = (const float*)d_in[2];
    const float* delta_log = (const float*)d_in[3];
    const float* r_log     = (const float*)d_in[4];
    float* out = (float*)d_out;

    const int n_waves = B_ * NRG * F_;         // 4096
    const int blocks  = n_waves / WPB;         // 1024
    pcen_kernel<<<blocks, TPB, 0, stream>>>(x, s_log, alpha_log, delta_log, r_log, out);
}